// Round 13
// baseline (150.125 us; speedup 1.0000x reference)
//
#include <hip/hip_runtime.h>
#include <hip/hip_bf16.h>
#include <hip/hip_fp16.h>

#define N_NODES 100000
#define D 64
#define N_EDGES 1250000

// fine buckets (sortgather granularity)
#define RB 64                   // nodes per fine bucket (dst>>6)
#define NB 1563                 // ceil(N / 64)
#define FCAP 1536               // fine slab capacity; mean 800, max ~950
#define SORT_CAP 1536

// coarse buckets (partition pass A)
#define CB_SHIFT 11             // 2048 nodes per coarse bucket
#define NCB 49                  // ceil(N / 2048)
#define CCAP 28672              // mean 25510, +20 sigma
#define FINE_PER_COARSE 32      // 2048/64

#define CPAD 16                 // cursor padding: one counter per 64B line

// R12 LESSON: removing partA's LDS-sort+sweep cost +4.7us (scattered 4-B
// coarse writes, r7's 5x L2 write-amp pathology). This round: r11 verbatim
// (best, 138.7) + sg degree-sort (wave divergence: E[max of 8 Poisson(12.5)]
// ~ 20 vs mean 12.5 -> 1.6x gather overhead) + z-row load hoist.
#define EPB 8192
#define PARTA_BLOCKS ((N_EDGES + EPB - 1) / EPB)   // 153
#define SEGS 16
#define SEG_CAP 1792

#define TNP 256                 // pre nodes per 1024-thread block
#define PRE_BLOCKS ((N_NODES + TNP - 1) / TNP)     // 391
#define FUSED_BLOCKS (PARTA_BLOCKS + PRE_BLOCKS)   // 544
#define NWAVE 16

#define XP 72                   // LDS fp16 row stride (64 + 8 pad)
#define SMEM_BYTES 55296        // union: pre 18,432+36,864; partA 39,680

#define SG_BPB 2                // sortgather buckets per block
#define SG_BLOCKS ((NB + SG_BPB - 1) / SG_BPB)     // 782 (all resident)

typedef unsigned short ushort_t;
typedef _Float16 half_t;
typedef __attribute__((ext_vector_type(8))) _Float16 half8;
typedef __attribute__((ext_vector_type(4))) float floatx4;

// ---------------------------------------------------------------------------
// Fused pre-transform + partition pass A (r11 form, unchanged).
// ---------------------------------------------------------------------------
__global__ __launch_bounds__(1024) void pre_part_kernel(
    const float* __restrict__ x, const float* __restrict__ W_l,
    const float* __restrict__ b_l, const float* __restrict__ W_r,
    ushort_t* __restrict__ y, ushort_t* __restrict__ z,
    const int* __restrict__ src, const int* __restrict__ dst,
    int* __restrict__ ccursor, unsigned* __restrict__ coarse,
    int N, int E)
{
    extern __shared__ char smem[];
    int t = threadIdx.x;

    if (blockIdx.x < PARTA_BLOCKS) {
        // ---------------- partA role: LDS counting sort + coalesced sweep ---
        int* hist16       = (int*)smem;               // [16][NCB] 3,136 B
        int* lbase        = (int*)(smem + 3200);      // [64] local excl base
        int* gbase        = (int*)(smem + 3456);      // [NCB]
        int* lwb          = (int*)(smem + 3712);      // [16][NCB] 3,136 B
        unsigned* sortedL = (unsigned*)(smem + 6912); // [EPB] 32,768 B
        const int w = t >> 6;

        if (t < NWAVE * NCB) hist16[t] = 0;
        __syncthreads();

        int base = blockIdx.x * EPB;
        int lim = E - base; if (lim > EPB) lim = EPB;

        for (int i = t; i < lim; i += 1024)
            atomicAdd(&hist16[w * NCB + (dst[base + i] >> CB_SHIFT)], 1);
        __syncthreads();

        if (t < 64) {   // lane-parallel scan + global reserve
            int cw[NWAVE]; int tot = 0;
            if (t < NCB) {
#pragma unroll
                for (int k = 0; k < NWAVE; k++) { cw[k] = hist16[k * NCB + t]; tot += cw[k]; }
            }
            int inc = tot;
#pragma unroll
            for (int off = 1; off < 64; off <<= 1) {
                int n = __shfl_up(inc, off, 64);
                if (t >= off) inc += n;
            }
            int ex = inc - tot;
            if (t < NCB) {
                lbase[t] = ex;
                gbase[t] = tot ? atomicAdd(&ccursor[t * CPAD], tot) : 0;
                int run = ex;
#pragma unroll
                for (int k = 0; k < NWAVE; k++) { lwb[k * NCB + t] = run; run += cw[k]; }
            } else {
                lbase[t] = lim;   // sentinel for binary search
            }
        }
        __syncthreads();

        for (int i = t; i < lim; i += 1024) {
            int d = dst[base + i];
            int s = src[base + i];
            int b = d >> CB_SHIFT;
            int pos = atomicSub(&hist16[w * NCB + b], 1) - 1;
            sortedL[lwb[w * NCB + b] + pos] =
                (unsigned)s | ((unsigned)(d & ((1 << CB_SHIFT) - 1)) << 17);
        }
        __syncthreads();

        // sweep: element i -> bucket = max b with lbase[b] <= i
        for (int i = t; i < lim; i += 1024) {
            int lo = 0;
#pragma unroll
            for (int s2 = 32; s2; s2 >>= 1) {
                int c = lo + s2;
                if (c < 64 && lbase[c] <= i) lo = c;
            }
            coarse[(size_t)lo * CCAP + gbase[lo] + (i - lbase[lo])] = sortedL[i];
        }
        return;
    }

    // ---------------- pre role (256 nodes, MFMA, LDS-staged output) --------
    half_t* sWt = (half_t*)smem;            // [128*XP] 18,432 B
    half_t* sXh = (half_t*)(smem + 18432);  // [TNP*XP] 36,864 B; Y/Z stage

    for (int i = t; i < 64 * 64; i += 1024) {
        int k = i >> 6, c = i & 63;
        sWt[c * XP + k]        = (half_t)W_l[i];
        sWt[(64 + c) * XP + k] = (half_t)W_r[i];
    }

    long base = (long)(blockIdx.x - PARTA_BLOCKS) * TNP;
    for (int i = t; i < TNP * 16; i += 1024) {   // 256 nodes x 16 float4
        int n = i >> 4, q = i & 15;
        long node = base + n;
        float4 v = make_float4(0.f, 0.f, 0.f, 0.f);
        if (node < N) v = ((const float4*)(x + node * D))[q];
        half_t* p = &sXh[n * XP + q * 4];
        p[0] = (half_t)v.x; p[1] = (half_t)v.y;
        p[2] = (half_t)v.z; p[3] = (half_t)v.w;
    }
    __syncthreads();

    const int lane  = t & 63;
    const int w     = t >> 6;        // wave id = node-tile 0..15
    const int col16 = lane & 15;
    const int quad  = lane >> 4;

    const int nrow = w * 16 + col16;
    half8 xb0 = *(half8*)&sXh[nrow * XP + quad * 8];
    half8 xb1 = *(half8*)&sXh[nrow * XP + 32 + quad * 8];

    float4 bq[4];
#pragma unroll
    for (int j = 0; j < 4; j++) bq[j] = *(const float4*)(b_l + j * 16 + quad * 4);

    // Y: ct 0..3 (stage into own rows; same-wave DS ordering)
#pragma unroll
    for (int ct = 0; ct < 4; ct++) {
        int c = ct * 16 + col16;
        half8 wa0 = *(half8*)&sWt[c * XP + quad * 8];
        half8 wa1 = *(half8*)&sWt[c * XP + 32 + quad * 8];
        floatx4 acc = {0.f, 0.f, 0.f, 0.f};
        acc = __builtin_amdgcn_mfma_f32_16x16x32_f16(wa0, xb0, acc, 0, 0, 0);
        acc = __builtin_amdgcn_mfma_f32_16x16x32_f16(wa1, xb1, acc, 0, 0, 0);
        union { half_t h[4]; uint2 u; } pk;
        pk.h[0] = (half_t)acc[0]; pk.h[1] = (half_t)acc[1];
        pk.h[2] = (half_t)acc[2]; pk.h[3] = (half_t)acc[3];
        *(uint2*)&sXh[nrow * XP + ct * 16 + quad * 4] = pk.u;
    }
    __syncthreads();

    for (int c2 = t; c2 < TNP * 8; c2 += 1024) {
        int row = c2 >> 3, f = c2 & 7;
        if (base + row < N)
            *(uint4*)(y + (base + row) * D + f * 8) = *(uint4*)&sXh[row * XP + f * 8];
    }
    __syncthreads();

    // Z: ct 4..7 with bias
#pragma unroll
    for (int ct = 4; ct < 8; ct++) {
        int c = ct * 16 + col16;
        half8 wa0 = *(half8*)&sWt[c * XP + quad * 8];
        half8 wa1 = *(half8*)&sWt[c * XP + 32 + quad * 8];
        floatx4 acc = {0.f, 0.f, 0.f, 0.f};
        acc = __builtin_amdgcn_mfma_f32_16x16x32_f16(wa0, xb0, acc, 0, 0, 0);
        acc = __builtin_amdgcn_mfma_f32_16x16x32_f16(wa1, xb1, acc, 0, 0, 0);
        float4 bv = bq[ct - 4];
        union { half_t h[4]; uint2 u; } pk;
        pk.h[0] = (half_t)(acc[0] + bv.x); pk.h[1] = (half_t)(acc[1] + bv.y);
        pk.h[2] = (half_t)(acc[2] + bv.z); pk.h[3] = (half_t)(acc[3] + bv.w);
        *(uint2*)&sXh[nrow * XP + (ct - 4) * 16 + quad * 4] = pk.u;
    }
    __syncthreads();

    for (int c2 = t; c2 < TNP * 8; c2 += 1024) {
        int row = c2 >> 3, f = c2 & 7;
        if (base + row < N)
            *(uint4*)(z + (base + row) * D + f * 8) = *(uint4*)&sXh[row * XP + f * 8];
    }
}

// ---------------------------------------------------------------------------
// Partition pass B (measured ~2us, unchanged).
// ---------------------------------------------------------------------------
__global__ __launch_bounds__(256) void partB_kernel(
    const unsigned* __restrict__ coarse, const int* __restrict__ ccursor,
    int* __restrict__ fcursor, unsigned* __restrict__ fine)
{
    __shared__ int hist4[4 * FINE_PER_COARSE];
    __shared__ int lbase2[FINE_PER_COARSE];
    __shared__ int gbase2[FINE_PER_COARSE];
    __shared__ int lwb2[4 * FINE_PER_COARSE];
    __shared__ unsigned sortedL[SEG_CAP];

    int cb = blockIdx.x >> 4;
    int seg = blockIdx.x & 15;
    int t = threadIdx.x;
    const int w = t >> 6;

    int cnt = ccursor[cb * CPAD];
    int segLen = (cnt + SEGS - 1) / SEGS;
    int beg = seg * segLen;
    int end = beg + segLen; if (end > cnt) end = cnt;
    int lim = end - beg; if (lim < 0) lim = 0;

    if (t < 4 * FINE_PER_COARSE) hist4[t] = 0;
    __syncthreads();

    const unsigned* __restrict__ slab = coarse + (size_t)cb * CCAP + beg;

    for (int i = t; i < lim; i += 256)
        atomicAdd(&hist4[w * FINE_PER_COARSE + ((slab[i] >> 17) >> 6)], 1);
    __syncthreads();

    if (t < 64) {
        int c0 = 0, c1 = 0, c2 = 0, c3 = 0, tot = 0;
        if (t < FINE_PER_COARSE) {
            c0 = hist4[t]; c1 = hist4[FINE_PER_COARSE + t];
            c2 = hist4[2 * FINE_PER_COARSE + t]; c3 = hist4[3 * FINE_PER_COARSE + t];
            tot = c0 + c1 + c2 + c3;
        }
        int inc = tot;
#pragma unroll
        for (int off = 1; off < 32; off <<= 1) {
            int n = __shfl_up(inc, off, 64);
            if (t >= off) inc += n;
        }
        int ex = inc - tot;
        if (t < FINE_PER_COARSE) {
            lbase2[t] = ex;
            int fb = cb * FINE_PER_COARSE + t;
            gbase2[t] = tot ? atomicAdd(&fcursor[fb * CPAD], tot) : 0;
            lwb2[t]                       = ex;
            lwb2[FINE_PER_COARSE + t]     = ex + c0;
            lwb2[2 * FINE_PER_COARSE + t] = ex + c0 + c1;
            lwb2[3 * FINE_PER_COARSE + t] = ex + c0 + c1 + c2;
        }
    }
    __syncthreads();

    for (int i = t; i < lim; i += 256) {
        unsigned e = slab[i];
        unsigned cl = e >> 17;
        int loc = cl >> 6;
        int pos = atomicSub(&hist4[w * FINE_PER_COARSE + loc], 1) - 1;
        sortedL[lwb2[w * FINE_PER_COARSE + loc] + pos] =
            (e & 0x1FFFFu) | ((cl & 63u) << 17);
    }
    __syncthreads();

    for (int i = t; i < lim; i += 256) {
        int lo = 0;
#pragma unroll
        for (int s2 = 16; s2; s2 >>= 1) {
            int c = lo + s2;
            if (c < FINE_PER_COARSE && lbase2[c] <= i) lo = c;
        }
        fine[((size_t)cb * FINE_PER_COARSE + lo) * FCAP + gbase2[lo] + (i - lbase2[lo])]
            = sortedL[i];
    }
}

// ---------------------------------------------------------------------------
// Fused sort + gather: 782 blocks x 2 buckets. NEW: degree-sort the 64 nodes
// (wave-0 bitonic over (deg,idx), tie-broken by idx -> exact permutation) so
// each wave handles 8 degree-similar nodes, killing the E[max of 8] ~ 1.6x
// gather divergence. z-row load hoisted above the gather loop.
// ---------------------------------------------------------------------------
__global__ __launch_bounds__(512) void sortgather_kernel(
    const ushort_t* __restrict__ y, const ushort_t* __restrict__ z,
    const unsigned* __restrict__ part, const int* __restrict__ cursor,
    float* __restrict__ out, int N)
{
    __shared__ int sorted[SORT_CAP];
    __shared__ int hist[RB];
    __shared__ int cur[RB];
    __shared__ int begL[RB];
    __shared__ int perm[RB];

    int t = threadIdx.x;

    for (int sub = 0; sub < SG_BPB; sub++) {
        int b = blockIdx.x * SG_BPB + sub;
        if (b >= NB) break;
        __syncthreads();   // prior bucket's gather done before LDS reuse

        int cnt = cursor[b * CPAD];
        if (cnt > SORT_CAP) cnt = SORT_CAP;
        const unsigned* __restrict__ slab = part + (size_t)b * FCAP;

        unsigned e0 = 0, e1 = 0, e2 = 0;
        int i0 = t, i1 = t + 512, i2 = t + 1024;
        if (i0 < cnt) e0 = slab[i0];
        if (i1 < cnt) e1 = slab[i1];
        if (i2 < cnt) e2 = slab[i2];

        if (t < RB) hist[t] = 0;
        __syncthreads();

        if (i0 < cnt) atomicAdd(&hist[e0 >> 17], 1);
        if (i1 < cnt) atomicAdd(&hist[e1 >> 17], 1);
        if (i2 < cnt) atomicAdd(&hist[e2 >> 17], 1);
        __syncthreads();

        if (t < RB) {
            int v = hist[t];
            int inc = v;
#pragma unroll
            for (int off = 1; off < RB; off <<= 1) {
                int n = __shfl_up(inc, off, RB);
                if (t >= off) inc += n;
            }
            int ex = inc - v;
            cur[t] = ex;
            begL[t] = ex;
        }
        __syncthreads();

        if (i0 < cnt) { int p = atomicAdd(&cur[e0 >> 17], 1); sorted[p] = (int)(e0 & 0x1FFFF); }
        if (i1 < cnt) { int p = atomicAdd(&cur[e1 >> 17], 1); sorted[p] = (int)(e1 & 0x1FFFF); }
        if (i2 < cnt) { int p = atomicAdd(&cur[e2 >> 17], 1); sorted[p] = (int)(e2 & 0x1FFFF); }

        // wave-0 bitonic sort of (deg, idx) ascending; runs concurrent with
        // other waves' scatter (reads hist only, writes perm only)
        if (t < 64) {
            int key = hist[t];
            int idx = t;
#pragma unroll
            for (int k = 2; k <= 64; k <<= 1) {
#pragma unroll
                for (int j = k >> 1; j > 0; j >>= 1) {
                    int pkey = __shfl_xor(key, j, 64);
                    int pidx = __shfl_xor(idx, j, 64);
                    bool up = ((t & k) == 0);
                    bool lower = ((t & j) == 0);
                    bool takeMin = (lower == up);
                    bool sw = takeMin ? (pkey < key || (pkey == key && pidx < idx))
                                      : (pkey > key || (pkey == key && pidx > idx));
                    if (sw) { key = pkey; idx = pidx; }
                }
            }
            perm[t] = idx;
        }
        __syncthreads();

        const int gp = t >> 3;        // physical group
        const int f = t & 7;
        const int node = perm[gp];    // degree-similar within each wave
        int myBeg = begL[node];
        int myDeg = hist[node];

        long gn = (long)b * RB + node;
        uint4 zr = make_uint4(0u, 0u, 0u, 0u);
        if (gn < N) zr = ((const uint4*)(z + (size_t)gn * D))[f];   // hoisted

        float2 acc0 = make_float2(0.f, 0.f), acc1 = acc0, acc2 = acc0, acc3 = acc0;

#define ACC(r) { \
        float2 c0 = __half22float2(*(const __half2*)&(r).x); \
        float2 c1 = __half22float2(*(const __half2*)&(r).y); \
        float2 c2 = __half22float2(*(const __half2*)&(r).z); \
        float2 c3 = __half22float2(*(const __half2*)&(r).w); \
        acc0.x += c0.x; acc0.y += c0.y; acc1.x += c1.x; acc1.y += c1.y; \
        acc2.x += c2.x; acc2.y += c2.y; acc3.x += c3.x; acc3.y += c3.y; }

        int i = 0;
        for (; i + 8 <= myDeg; i += 8) {
            int s0 = sorted[myBeg + i];
            int s1 = sorted[myBeg + i + 1];
            int s2 = sorted[myBeg + i + 2];
            int s3 = sorted[myBeg + i + 3];
            int s4 = sorted[myBeg + i + 4];
            int s5 = sorted[myBeg + i + 5];
            int s6 = sorted[myBeg + i + 6];
            int s7 = sorted[myBeg + i + 7];
            uint4 r0 = ((const uint4*)(y + (size_t)s0 * D))[f];
            uint4 r1 = ((const uint4*)(y + (size_t)s1 * D))[f];
            uint4 r2 = ((const uint4*)(y + (size_t)s2 * D))[f];
            uint4 r3 = ((const uint4*)(y + (size_t)s3 * D))[f];
            uint4 r4 = ((const uint4*)(y + (size_t)s4 * D))[f];
            uint4 r5 = ((const uint4*)(y + (size_t)s5 * D))[f];
            uint4 r6 = ((const uint4*)(y + (size_t)s6 * D))[f];
            uint4 r7 = ((const uint4*)(y + (size_t)s7 * D))[f];
            ACC(r0) ACC(r1) ACC(r2) ACC(r3) ACC(r4) ACC(r5) ACC(r6) ACC(r7)
        }
        for (; i + 4 <= myDeg; i += 4) {
            int s0 = sorted[myBeg + i];
            int s1 = sorted[myBeg + i + 1];
            int s2 = sorted[myBeg + i + 2];
            int s3 = sorted[myBeg + i + 3];
            uint4 r0 = ((const uint4*)(y + (size_t)s0 * D))[f];
            uint4 r1 = ((const uint4*)(y + (size_t)s1 * D))[f];
            uint4 r2 = ((const uint4*)(y + (size_t)s2 * D))[f];
            uint4 r3 = ((const uint4*)(y + (size_t)s3 * D))[f];
            ACC(r0) ACC(r1) ACC(r2) ACC(r3)
        }
        for (; i < myDeg; i++) {
            int s = sorted[myBeg + i];
            uint4 r = ((const uint4*)(y + (size_t)s * D))[f];
            ACC(r)
        }
#undef ACC

        if (gn < N) {
            float2 z0 = __half22float2(*(const __half2*)&zr.x);
            float2 z1 = __half22float2(*(const __half2*)&zr.y);
            float2 z2 = __half22float2(*(const __half2*)&zr.z);
            float2 z3 = __half22float2(*(const __half2*)&zr.w);
            float4 o0, o1;
            o0.x = tanhf(acc0.x + z0.x); o0.y = tanhf(acc0.y + z0.y);
            o0.z = tanhf(acc1.x + z1.x); o0.w = tanhf(acc1.y + z1.y);
            o1.x = tanhf(acc2.x + z2.x); o1.y = tanhf(acc2.y + z2.y);
            o1.z = tanhf(acc3.x + z3.x); o1.w = tanhf(acc3.y + z3.y);
            float4* op = (float4*)(out + gn * D);
            op[2 * f] = o0;
            op[2 * f + 1] = o1;
        }
    }
}

extern "C" void kernel_launch(void* const* d_in, const int* in_sizes, int n_in,
                              void* d_out, int out_size, void* d_ws, size_t ws_size,
                              hipStream_t stream) {
    const float* x   = (const float*)d_in[0];
    const int* ei    = (const int*)d_in[1];   // [2,E] int32
    const float* W_l = (const float*)d_in[2];
    const float* b_l = (const float*)d_in[3];
    const float* W_r = (const float*)d_in[4];
    float* out = (float*)d_out;

    const int N = N_NODES;
    const int E = N_EDGES;
    const int* src = ei;
    const int* dst = ei + E;

    // workspace layout (ws is 268 MB)
    char* ws = (char*)d_ws;
    ushort_t* y      = (ushort_t*)(ws);                  // 12,800,000 B
    ushort_t* z      = (ushort_t*)(ws + 12800000);       // 12,800,000 B
    unsigned* coarse = (unsigned*)(ws + 25600000);       // 5,619,712 B
    unsigned* fine   = (unsigned*)(ws + 31219712);       // 9,603,072 B
    int* ccursor     = (int*)(ws + 40822784);            // 3,136 B (line-padded)
    int* fcursor     = (int*)(ws + 40825920);            // 100,032 B (line-padded)

    // zero both padded cursor arrays (adjacent): 3,136 + 100,032 B
    hipMemsetAsync(ccursor, 0, 103168, stream);

    pre_part_kernel<<<FUSED_BLOCKS, 1024, SMEM_BYTES, stream>>>(
        x, W_l, b_l, W_r, y, z, src, dst, ccursor, coarse, N, E);
    partB_kernel<<<NCB * SEGS, 256, 0, stream>>>(coarse, ccursor, fcursor, fine);
    sortgather_kernel<<<SG_BLOCKS, 512, 0, stream>>>(y, z, fine, fcursor, out, N);
}

// Round 14
// 140.321 us; speedup vs baseline: 1.0699x; 1.0699x over previous
//
#include <hip/hip_runtime.h>
#include <hip/hip_bf16.h>
#include <hip/hip_fp16.h>

#define N_NODES 100000
#define D 64
#define N_EDGES 1250000

// fine buckets (sortgather granularity)
#define RB 64                   // nodes per fine bucket (dst>>6)
#define NB 1563                 // ceil(N / 64)
#define FCAP 1536               // fine slab capacity; mean 800, max ~950
#define SORT_CAP 1536

// coarse buckets (partition pass A)
#define CB_SHIFT 11             // 2048 nodes per coarse bucket
#define NCB 49                  // ceil(N / 2048)
#define CCAP 28672              // mean 25510, +20 sigma
#define FINE_PER_COARSE 32      // 2048/64

#define CPAD 16                 // cursor padding: one counter per 64B line

// R13 LESSON: sg degree-sort permutation cost +17us (scattered output rows,
// broken gather locality) -> reverted. This round = r11 verbatim (best,
// 138.7) + ONE micro-fix: sg z-row load hoisted above the gather loop.
#define EPB 8192
#define PARTA_BLOCKS ((N_EDGES + EPB - 1) / EPB)   // 153
#define SEGS 16
#define SEG_CAP 1792

#define TNP 256                 // pre nodes per 1024-thread block
#define PRE_BLOCKS ((N_NODES + TNP - 1) / TNP)     // 391
#define FUSED_BLOCKS (PARTA_BLOCKS + PRE_BLOCKS)   // 544
#define NWAVE 16

#define XP 72                   // LDS fp16 row stride (64 + 8 pad)
#define SMEM_BYTES 55296        // union: pre 18,432+36,864; partA 39,680

#define SG_BPB 2                // sortgather buckets per block
#define SG_BLOCKS ((NB + SG_BPB - 1) / SG_BPB)     // 782 (all resident)

typedef unsigned short ushort_t;
typedef _Float16 half_t;
typedef __attribute__((ext_vector_type(8))) _Float16 half8;
typedef __attribute__((ext_vector_type(4))) float floatx4;

// ---------------------------------------------------------------------------
// Fused pre-transform + partition pass A (r11 form, unchanged).
// partA (blocks 0..152): per-wave LDS hist, wave-0 scan + padded cursor
//   reserve, LDS counting sort, coalesced sweep (~668-B runs).
// pre (blocks 153..): 256 nodes/block; [Y|Z] = X @ [W_l|W_r] fp16 MFMA;
//   LDS-staged 128-B-row output sweeps.
// ---------------------------------------------------------------------------
__global__ __launch_bounds__(1024) void pre_part_kernel(
    const float* __restrict__ x, const float* __restrict__ W_l,
    const float* __restrict__ b_l, const float* __restrict__ W_r,
    ushort_t* __restrict__ y, ushort_t* __restrict__ z,
    const int* __restrict__ src, const int* __restrict__ dst,
    int* __restrict__ ccursor, unsigned* __restrict__ coarse,
    int N, int E)
{
    extern __shared__ char smem[];
    int t = threadIdx.x;

    if (blockIdx.x < PARTA_BLOCKS) {
        // ---------------- partA role: LDS counting sort + coalesced sweep ---
        int* hist16       = (int*)smem;               // [16][NCB] 3,136 B
        int* lbase        = (int*)(smem + 3200);      // [64] local excl base
        int* gbase        = (int*)(smem + 3456);      // [NCB]
        int* lwb          = (int*)(smem + 3712);      // [16][NCB] 3,136 B
        unsigned* sortedL = (unsigned*)(smem + 6912); // [EPB] 32,768 B
        const int w = t >> 6;

        if (t < NWAVE * NCB) hist16[t] = 0;
        __syncthreads();

        int base = blockIdx.x * EPB;
        int lim = E - base; if (lim > EPB) lim = EPB;

        for (int i = t; i < lim; i += 1024)
            atomicAdd(&hist16[w * NCB + (dst[base + i] >> CB_SHIFT)], 1);
        __syncthreads();

        if (t < 64) {   // lane-parallel scan + global reserve
            int cw[NWAVE]; int tot = 0;
            if (t < NCB) {
#pragma unroll
                for (int k = 0; k < NWAVE; k++) { cw[k] = hist16[k * NCB + t]; tot += cw[k]; }
            }
            int inc = tot;
#pragma unroll
            for (int off = 1; off < 64; off <<= 1) {
                int n = __shfl_up(inc, off, 64);
                if (t >= off) inc += n;
            }
            int ex = inc - tot;
            if (t < NCB) {
                lbase[t] = ex;
                gbase[t] = tot ? atomicAdd(&ccursor[t * CPAD], tot) : 0;
                int run = ex;
#pragma unroll
                for (int k = 0; k < NWAVE; k++) { lwb[k * NCB + t] = run; run += cw[k]; }
            } else {
                lbase[t] = lim;   // sentinel for binary search
            }
        }
        __syncthreads();

        for (int i = t; i < lim; i += 1024) {
            int d = dst[base + i];
            int s = src[base + i];
            int b = d >> CB_SHIFT;
            int pos = atomicSub(&hist16[w * NCB + b], 1) - 1;
            sortedL[lwb[w * NCB + b] + pos] =
                (unsigned)s | ((unsigned)(d & ((1 << CB_SHIFT) - 1)) << 17);
        }
        __syncthreads();

        // sweep: element i -> bucket = max b with lbase[b] <= i
        for (int i = t; i < lim; i += 1024) {
            int lo = 0;
#pragma unroll
            for (int s2 = 32; s2; s2 >>= 1) {
                int c = lo + s2;
                if (c < 64 && lbase[c] <= i) lo = c;
            }
            coarse[(size_t)lo * CCAP + gbase[lo] + (i - lbase[lo])] = sortedL[i];
        }
        return;
    }

    // ---------------- pre role (256 nodes, MFMA, LDS-staged output) --------
    half_t* sWt = (half_t*)smem;            // [128*XP] 18,432 B
    half_t* sXh = (half_t*)(smem + 18432);  // [TNP*XP] 36,864 B; Y/Z stage

    for (int i = t; i < 64 * 64; i += 1024) {
        int k = i >> 6, c = i & 63;
        sWt[c * XP + k]        = (half_t)W_l[i];
        sWt[(64 + c) * XP + k] = (half_t)W_r[i];
    }

    long base = (long)(blockIdx.x - PARTA_BLOCKS) * TNP;
    for (int i = t; i < TNP * 16; i += 1024) {   // 256 nodes x 16 float4
        int n = i >> 4, q = i & 15;
        long node = base + n;
        float4 v = make_float4(0.f, 0.f, 0.f, 0.f);
        if (node < N) v = ((const float4*)(x + node * D))[q];
        half_t* p = &sXh[n * XP + q * 4];
        p[0] = (half_t)v.x; p[1] = (half_t)v.y;
        p[2] = (half_t)v.z; p[3] = (half_t)v.w;
    }
    __syncthreads();

    const int lane  = t & 63;
    const int w     = t >> 6;        // wave id = node-tile 0..15
    const int col16 = lane & 15;
    const int quad  = lane >> 4;

    const int nrow = w * 16 + col16;
    half8 xb0 = *(half8*)&sXh[nrow * XP + quad * 8];
    half8 xb1 = *(half8*)&sXh[nrow * XP + 32 + quad * 8];

    float4 bq[4];
#pragma unroll
    for (int j = 0; j < 4; j++) bq[j] = *(const float4*)(b_l + j * 16 + quad * 4);

    // Y: ct 0..3 (stage into own rows; same-wave DS ordering)
#pragma unroll
    for (int ct = 0; ct < 4; ct++) {
        int c = ct * 16 + col16;
        half8 wa0 = *(half8*)&sWt[c * XP + quad * 8];
        half8 wa1 = *(half8*)&sWt[c * XP + 32 + quad * 8];
        floatx4 acc = {0.f, 0.f, 0.f, 0.f};
        acc = __builtin_amdgcn_mfma_f32_16x16x32_f16(wa0, xb0, acc, 0, 0, 0);
        acc = __builtin_amdgcn_mfma_f32_16x16x32_f16(wa1, xb1, acc, 0, 0, 0);
        union { half_t h[4]; uint2 u; } pk;
        pk.h[0] = (half_t)acc[0]; pk.h[1] = (half_t)acc[1];
        pk.h[2] = (half_t)acc[2]; pk.h[3] = (half_t)acc[3];
        *(uint2*)&sXh[nrow * XP + ct * 16 + quad * 4] = pk.u;
    }
    __syncthreads();

    for (int c2 = t; c2 < TNP * 8; c2 += 1024) {
        int row = c2 >> 3, f = c2 & 7;
        if (base + row < N)
            *(uint4*)(y + (base + row) * D + f * 8) = *(uint4*)&sXh[row * XP + f * 8];
    }
    __syncthreads();

    // Z: ct 4..7 with bias
#pragma unroll
    for (int ct = 4; ct < 8; ct++) {
        int c = ct * 16 + col16;
        half8 wa0 = *(half8*)&sWt[c * XP + quad * 8];
        half8 wa1 = *(half8*)&sWt[c * XP + 32 + quad * 8];
        floatx4 acc = {0.f, 0.f, 0.f, 0.f};
        acc = __builtin_amdgcn_mfma_f32_16x16x32_f16(wa0, xb0, acc, 0, 0, 0);
        acc = __builtin_amdgcn_mfma_f32_16x16x32_f16(wa1, xb1, acc, 0, 0, 0);
        float4 bv = bq[ct - 4];
        union { half_t h[4]; uint2 u; } pk;
        pk.h[0] = (half_t)(acc[0] + bv.x); pk.h[1] = (half_t)(acc[1] + bv.y);
        pk.h[2] = (half_t)(acc[2] + bv.z); pk.h[3] = (half_t)(acc[3] + bv.w);
        *(uint2*)&sXh[nrow * XP + (ct - 4) * 16 + quad * 4] = pk.u;
    }
    __syncthreads();

    for (int c2 = t; c2 < TNP * 8; c2 += 1024) {
        int row = c2 >> 3, f = c2 & 7;
        if (base + row < N)
            *(uint4*)(z + (base + row) * D + f * 8) = *(uint4*)&sXh[row * XP + f * 8];
    }
}

// ---------------------------------------------------------------------------
// Partition pass B (measured ~2us, unchanged).
// ---------------------------------------------------------------------------
__global__ __launch_bounds__(256) void partB_kernel(
    const unsigned* __restrict__ coarse, const int* __restrict__ ccursor,
    int* __restrict__ fcursor, unsigned* __restrict__ fine)
{
    __shared__ int hist4[4 * FINE_PER_COARSE];
    __shared__ int lbase2[FINE_PER_COARSE];
    __shared__ int gbase2[FINE_PER_COARSE];
    __shared__ int lwb2[4 * FINE_PER_COARSE];
    __shared__ unsigned sortedL[SEG_CAP];

    int cb = blockIdx.x >> 4;
    int seg = blockIdx.x & 15;
    int t = threadIdx.x;
    const int w = t >> 6;

    int cnt = ccursor[cb * CPAD];
    int segLen = (cnt + SEGS - 1) / SEGS;
    int beg = seg * segLen;
    int end = beg + segLen; if (end > cnt) end = cnt;
    int lim = end - beg; if (lim < 0) lim = 0;

    if (t < 4 * FINE_PER_COARSE) hist4[t] = 0;
    __syncthreads();

    const unsigned* __restrict__ slab = coarse + (size_t)cb * CCAP + beg;

    for (int i = t; i < lim; i += 256)
        atomicAdd(&hist4[w * FINE_PER_COARSE + ((slab[i] >> 17) >> 6)], 1);
    __syncthreads();

    if (t < 64) {
        int c0 = 0, c1 = 0, c2 = 0, c3 = 0, tot = 0;
        if (t < FINE_PER_COARSE) {
            c0 = hist4[t]; c1 = hist4[FINE_PER_COARSE + t];
            c2 = hist4[2 * FINE_PER_COARSE + t]; c3 = hist4[3 * FINE_PER_COARSE + t];
            tot = c0 + c1 + c2 + c3;
        }
        int inc = tot;
#pragma unroll
        for (int off = 1; off < 32; off <<= 1) {
            int n = __shfl_up(inc, off, 64);
            if (t >= off) inc += n;
        }
        int ex = inc - tot;
        if (t < FINE_PER_COARSE) {
            lbase2[t] = ex;
            int fb = cb * FINE_PER_COARSE + t;
            gbase2[t] = tot ? atomicAdd(&fcursor[fb * CPAD], tot) : 0;
            lwb2[t]                       = ex;
            lwb2[FINE_PER_COARSE + t]     = ex + c0;
            lwb2[2 * FINE_PER_COARSE + t] = ex + c0 + c1;
            lwb2[3 * FINE_PER_COARSE + t] = ex + c0 + c1 + c2;
        }
    }
    __syncthreads();

    for (int i = t; i < lim; i += 256) {
        unsigned e = slab[i];
        unsigned cl = e >> 17;
        int loc = cl >> 6;
        int pos = atomicSub(&hist4[w * FINE_PER_COARSE + loc], 1) - 1;
        sortedL[lwb2[w * FINE_PER_COARSE + loc] + pos] =
            (e & 0x1FFFFu) | ((cl & 63u) << 17);
    }
    __syncthreads();

    for (int i = t; i < lim; i += 256) {
        int lo = 0;
#pragma unroll
        for (int s2 = 16; s2; s2 >>= 1) {
            int c = lo + s2;
            if (c < FINE_PER_COARSE && lbase2[c] <= i) lo = c;
        }
        fine[((size_t)cb * FINE_PER_COARSE + lo) * FCAP + gbase2[lo] + (i - lbase2[lo])]
            = sortedL[i];
    }
}

// ---------------------------------------------------------------------------
// Fused sort + gather: 782 blocks x 2 buckets (r11 form, identity node
// mapping). ONLY change vs r11: z-row load hoisted above the gather loop
// so its latency hides under the gather instead of serializing after it.
// ---------------------------------------------------------------------------
__global__ __launch_bounds__(512) void sortgather_kernel(
    const ushort_t* __restrict__ y, const ushort_t* __restrict__ z,
    const unsigned* __restrict__ part, const int* __restrict__ cursor,
    float* __restrict__ out, int N)
{
    __shared__ int sorted[SORT_CAP];
    __shared__ int hist[RB];
    __shared__ int cur[RB];
    __shared__ int begL[RB];

    int t = threadIdx.x;

    for (int sub = 0; sub < SG_BPB; sub++) {
        int b = blockIdx.x * SG_BPB + sub;
        if (b >= NB) break;
        __syncthreads();   // prior bucket's gather done before LDS reuse

        int cnt = cursor[b * CPAD];
        if (cnt > SORT_CAP) cnt = SORT_CAP;
        const unsigned* __restrict__ slab = part + (size_t)b * FCAP;

        unsigned e0 = 0, e1 = 0, e2 = 0;
        int i0 = t, i1 = t + 512, i2 = t + 1024;
        if (i0 < cnt) e0 = slab[i0];
        if (i1 < cnt) e1 = slab[i1];
        if (i2 < cnt) e2 = slab[i2];

        if (t < RB) hist[t] = 0;
        __syncthreads();

        if (i0 < cnt) atomicAdd(&hist[e0 >> 17], 1);
        if (i1 < cnt) atomicAdd(&hist[e1 >> 17], 1);
        if (i2 < cnt) atomicAdd(&hist[e2 >> 17], 1);
        __syncthreads();

        if (t < RB) {
            int v = hist[t];
            int inc = v;
#pragma unroll
            for (int off = 1; off < RB; off <<= 1) {
                int n = __shfl_up(inc, off, RB);
                if (t >= off) inc += n;
            }
            int ex = inc - v;
            cur[t] = ex;
            begL[t] = ex;
        }
        __syncthreads();

        if (i0 < cnt) { int p = atomicAdd(&cur[e0 >> 17], 1); sorted[p] = (int)(e0 & 0x1FFFF); }
        if (i1 < cnt) { int p = atomicAdd(&cur[e1 >> 17], 1); sorted[p] = (int)(e1 & 0x1FFFF); }
        if (i2 < cnt) { int p = atomicAdd(&cur[e2 >> 17], 1); sorted[p] = (int)(e2 & 0x1FFFF); }
        __syncthreads();

        const int g = t >> 3;
        const int f = t & 7;
        int myBeg = begL[g];
        int myDeg = hist[g];

        long gn = (long)b * RB + g;
        uint4 zr = make_uint4(0u, 0u, 0u, 0u);
        if (gn < N) zr = ((const uint4*)(z + (size_t)gn * D))[f];   // hoisted

        float2 acc0 = make_float2(0.f, 0.f), acc1 = acc0, acc2 = acc0, acc3 = acc0;

#define ACC(r) { \
        float2 c0 = __half22float2(*(const __half2*)&(r).x); \
        float2 c1 = __half22float2(*(const __half2*)&(r).y); \
        float2 c2 = __half22float2(*(const __half2*)&(r).z); \
        float2 c3 = __half22float2(*(const __half2*)&(r).w); \
        acc0.x += c0.x; acc0.y += c0.y; acc1.x += c1.x; acc1.y += c1.y; \
        acc2.x += c2.x; acc2.y += c2.y; acc3.x += c3.x; acc3.y += c3.y; }

        int i = 0;
        for (; i + 8 <= myDeg; i += 8) {
            int s0 = sorted[myBeg + i];
            int s1 = sorted[myBeg + i + 1];
            int s2 = sorted[myBeg + i + 2];
            int s3 = sorted[myBeg + i + 3];
            int s4 = sorted[myBeg + i + 4];
            int s5 = sorted[myBeg + i + 5];
            int s6 = sorted[myBeg + i + 6];
            int s7 = sorted[myBeg + i + 7];
            uint4 r0 = ((const uint4*)(y + (size_t)s0 * D))[f];
            uint4 r1 = ((const uint4*)(y + (size_t)s1 * D))[f];
            uint4 r2 = ((const uint4*)(y + (size_t)s2 * D))[f];
            uint4 r3 = ((const uint4*)(y + (size_t)s3 * D))[f];
            uint4 r4 = ((const uint4*)(y + (size_t)s4 * D))[f];
            uint4 r5 = ((const uint4*)(y + (size_t)s5 * D))[f];
            uint4 r6 = ((const uint4*)(y + (size_t)s6 * D))[f];
            uint4 r7 = ((const uint4*)(y + (size_t)s7 * D))[f];
            ACC(r0) ACC(r1) ACC(r2) ACC(r3) ACC(r4) ACC(r5) ACC(r6) ACC(r7)
        }
        for (; i + 4 <= myDeg; i += 4) {
            int s0 = sorted[myBeg + i];
            int s1 = sorted[myBeg + i + 1];
            int s2 = sorted[myBeg + i + 2];
            int s3 = sorted[myBeg + i + 3];
            uint4 r0 = ((const uint4*)(y + (size_t)s0 * D))[f];
            uint4 r1 = ((const uint4*)(y + (size_t)s1 * D))[f];
            uint4 r2 = ((const uint4*)(y + (size_t)s2 * D))[f];
            uint4 r3 = ((const uint4*)(y + (size_t)s3 * D))[f];
            ACC(r0) ACC(r1) ACC(r2) ACC(r3)
        }
        for (; i < myDeg; i++) {
            int s = sorted[myBeg + i];
            uint4 r = ((const uint4*)(y + (size_t)s * D))[f];
            ACC(r)
        }
#undef ACC

        if (gn < N) {
            float2 z0 = __half22float2(*(const __half2*)&zr.x);
            float2 z1 = __half22float2(*(const __half2*)&zr.y);
            float2 z2 = __half22float2(*(const __half2*)&zr.z);
            float2 z3 = __half22float2(*(const __half2*)&zr.w);
            float4 o0, o1;
            o0.x = tanhf(acc0.x + z0.x); o0.y = tanhf(acc0.y + z0.y);
            o0.z = tanhf(acc1.x + z1.x); o0.w = tanhf(acc1.y + z1.y);
            o1.x = tanhf(acc2.x + z2.x); o1.y = tanhf(acc2.y + z2.y);
            o1.z = tanhf(acc3.x + z3.x); o1.w = tanhf(acc3.y + z3.y);
            float4* op = (float4*)(out + gn * D);
            op[2 * f] = o0;
            op[2 * f + 1] = o1;
        }
    }
}

extern "C" void kernel_launch(void* const* d_in, const int* in_sizes, int n_in,
                              void* d_out, int out_size, void* d_ws, size_t ws_size,
                              hipStream_t stream) {
    const float* x   = (const float*)d_in[0];
    const int* ei    = (const int*)d_in[1];   // [2,E] int32
    const float* W_l = (const float*)d_in[2];
    const float* b_l = (const float*)d_in[3];
    const float* W_r = (const float*)d_in[4];
    float* out = (float*)d_out;

    const int N = N_NODES;
    const int E = N_EDGES;
    const int* src = ei;
    const int* dst = ei + E;

    // workspace layout (ws is 268 MB)
    char* ws = (char*)d_ws;
    ushort_t* y      = (ushort_t*)(ws);                  // 12,800,000 B
    ushort_t* z      = (ushort_t*)(ws + 12800000);       // 12,800,000 B
    unsigned* coarse = (unsigned*)(ws + 25600000);       // 5,619,712 B
    unsigned* fine   = (unsigned*)(ws + 31219712);       // 9,603,072 B
    int* ccursor     = (int*)(ws + 40822784);            // 3,136 B (line-padded)
    int* fcursor     = (int*)(ws + 40825920);            // 100,032 B (line-padded)

    // zero both padded cursor arrays (adjacent): 3,136 + 100,032 B
    hipMemsetAsync(ccursor, 0, 103168, stream);

    pre_part_kernel<<<FUSED_BLOCKS, 1024, SMEM_BYTES, stream>>>(
        x, W_l, b_l, W_r, y, z, src, dst, ccursor, coarse, N, E);
    partB_kernel<<<NCB * SEGS, 256, 0, stream>>>(coarse, ccursor, fcursor, fine);
    sortgather_kernel<<<SG_BLOCKS, 512, 0, stream>>>(y, z, fine, fcursor, out, N);
}